// Round 4
// baseline (65.524 us; speedup 1.0000x reference)
//
#include <hip/hip_runtime.h>
#include <hip/hip_bf16.h>

// Exact Euclidean distance transform of a binary mask.
// B=4, C=1, H=W=384. Output = sqrt(exact squared EDT), float32.
//
// Single fused kernel, one block per image row (384 threads, y uniform):
//  1. ballot-pack own row's "is-zero" bits into LDS (6 u64 = 384 bits)
//  2. per-lane r0 = in-row distance to nearest zero; best = r0^2
//     (zero-free row -> r0 = 768, 768^2 = 589824 = LARGE: matches ref exactly)
//  3. block-reduce R = min(max_lane r0, 383). Cutoff argument: a lane scans
//     dy only while dy^2 < best <= r0^2, so dy <= r0 <= R -> packing rows
//     [y-R, y+R] is provably sufficient for an EXACT result.
//  4. ballot-pack that row range from mask (coalesced, L2-resident)
//  5. outward row scan from LDS bits with exact break dy^2 >= best
// All values are integers <= 736513 < 2^24 -> fp32 sqrt input is exact.

#define HH 384
#define WW 384
#define NB 4
#define WPR 6                      // u64 words per 384-bit row
#define NOZERO 768                 // 768^2 == 589824 == LARGE

typedef unsigned long long u64;

__device__ __forceinline__ int rowdist_lds(const u64* zr, int x) {
    // distance from column x to nearest set bit in this 384-bit row
    const int w = x >> 6, xin = x & 63;
    const u64 cur = zr[w];
    int dr = NOZERO, dl = NOZERO;
    u64 t = cur >> xin;                           // bits at positions >= x
    if (t) {
        dr = __ffsll((long long)t) - 1;
    } else {
        for (int ww = w + 1; ww < WPR; ++ww) {
            u64 v = zr[ww];
            if (v) { dr = (ww << 6) + __ffsll((long long)v) - 1 - x; break; }
        }
    }
    u64 u = cur << (63 - xin);                    // bit x -> bit 63
    if (u) {
        dl = __clzll((long long)u);
    } else {
        for (int ww = w - 1; ww >= 0; --ww) {
            u64 v = zr[ww];
            if (v) { dl = x - ((ww << 6) + 63 - __clzll((long long)v)); break; }
        }
    }
    return min(dl, dr);                           // NOZERO if row has no zeros
}

__global__ __launch_bounds__(WW) void edt_fused(const float* __restrict__ mask,
                                                float* __restrict__ out) {
    const int rid = blockIdx.x;        // b*HH + y
    const int b = rid / HH;
    const int y = rid % HH;
    const int x = threadIdx.x;         // 0..383
    const int wid = x >> 6;            // wave id = word id

    __shared__ u64 bits[HH][WPR];
    __shared__ int smax[WW / 64];

    const float* mb = mask + (size_t)b * HH * WW;

    // 1. pack own row
    {
        u64 w = __ballot(mb[y * WW + x] < 0.5f);
        if ((x & 63) == 0) bits[y][wid] = w;
    }
    __syncthreads();

    // 2. own-row distance
    int r0 = rowdist_lds(bits[y], x);
    int best = r0 * r0;

    // 3. block max of r0 -> packing radius R
    int m = r0;
    #pragma unroll
    for (int off = 32; off; off >>= 1) m = max(m, __shfl_xor(m, off));
    if ((x & 63) == 0) smax[wid] = m;
    __syncthreads();
    int R = smax[0];
    #pragma unroll
    for (int i = 1; i < WW / 64; ++i) R = max(R, smax[i]);
    R = min(R, HH - 1);

    // 4. pack rows [y-R, y+R] (clipped); own row already done.
    //    Loop bounds are block-uniform -> ballots are safe.
    const int lo = max(0, y - R), hi = min(HH - 1, y + R);
    for (int r = lo; r <= hi; ++r) {
        if (r == y) continue;
        u64 w = __ballot(mb[r * WW + x] < 0.5f);
        if ((x & 63) == 0) bits[r][wid] = w;
    }
    __syncthreads();

    // 5. outward scan with exact cutoff
    for (int dy = 1; dy <= R; ++dy) {
        int dd = dy * dy;
        if (dd >= best) break;
        if (y - dy >= 0) {
            int r = rowdist_lds(bits[y - dy], x);
            best = min(best, dd + r * r);
        }
        if (y + dy < HH) {
            int r = rowdist_lds(bits[y + dy], x);
            best = min(best, dd + r * r);
        }
    }
    out[(size_t)rid * WW + x] = sqrtf((float)best);
}

extern "C" void kernel_launch(void* const* d_in, const int* in_sizes, int n_in,
                              void* d_out, int out_size, void* d_ws, size_t ws_size,
                              hipStream_t stream) {
    const float* mask = (const float*)d_in[0];
    float* out = (float*)d_out;
    edt_fused<<<NB * HH, WW, 0, stream>>>(mask, out);
}

// Round 6
// 58.559 us; speedup vs baseline: 1.1189x; 1.1189x over previous
//
#include <hip/hip_runtime.h>
#include <hip/hip_bf16.h>

// Exact Euclidean distance transform of a binary mask.
// B=4, C=1, H=W=384. Output = sqrt(exact squared EDT), float32.
//
// Two kernels:
//  1. pack_zbits: ballot-pack "is-zero" pixels into u64 bitrows
//     (384 bits = 6 words/row, 73728 B total, L2-resident).
//  2. edt_solve_row: one block per image row. Bulk-stage the packed bits
//     of rows [y-16, y+16] into LDS (198 u64, one coalesced burst, ONE
//     barrier), then per-pixel: r0 = in-row nearest-zero distance via
//     ffs/clz, best = r0^2, outward row scan with the EXACT cutoff
//     dy^2 >= best (any unscanned row at distance dy contributes >= dy^2).
//     Rows beyond the staged +-16 window (needed only if best > 289,
//     P ~ 2^-35 per pixel -- includes the zero-free-row case) read global
//     zbits directly, preserving exactness.
// Zero-free rows give rowdist = 768; 768^2 = 589824 = LARGE = 2*(H^2+W^2),
// matching the reference's LARGE term exactly.
// All values are integers <= 736513 < 2^24 -> fp32 sqrt input is exact.
// All rowdist LDS reads are wave-uniform (word id == wave id) -> broadcast,
// zero bank conflicts.

#define HH 384
#define WW 384
#define NB 4
#define WPR 6                      // u64 words per 384-bit row
#define NPIX (NB * HH * WW)
#define NWORDS (NB * HH * WPR)     // 9216
#define NOZERO 768                 // 768^2 == 589824 == LARGE
#define RSTAGE 16                  // staged row radius

typedef unsigned long long u64;

// ---------- kernel 1: pack ----------

__global__ __launch_bounds__(256) void pack_zbits(const float* __restrict__ mask,
                                                  u64* __restrict__ zbits) {
    int idx = blockIdx.x * 256 + threadIdx.x;     // grid is exact (NPIX/256)
    u64 w = __ballot(mask[idx] < 0.5f);           // 64 consecutive x, one row
    if ((threadIdx.x & 63) == 0) zbits[idx >> 6] = w;
}

// ---------- rowdist: distance from col x to nearest set bit in a 384-bit row

template <typename PT>
__device__ __forceinline__ int rowdist_t(PT zr, int x) {
    const int w = x >> 6, xin = x & 63;
    const u64 cur = zr[w];
    int dr = NOZERO, dl = NOZERO;
    u64 t = cur >> xin;                           // bits at positions >= x
    if (t) {
        dr = __ffsll((long long)t) - 1;
    } else {
        for (int ww = w + 1; ww < WPR; ++ww) {
            u64 v = zr[ww];
            if (v) { dr = (ww << 6) + __ffsll((long long)v) - 1 - x; break; }
        }
    }
    u64 u = cur << (63 - xin);                    // bit x -> bit 63
    if (u) {
        dl = __clzll((long long)u);
    } else {
        for (int ww = w - 1; ww >= 0; --ww) {
            u64 v = zr[ww];
            if (v) { dl = x - ((ww << 6) + 63 - __clzll((long long)v)); break; }
        }
    }
    return min(dl, dr);                           // NOZERO if row has no zeros
}

// ---------- kernel 2: solve, one block per row ----------

__global__ __launch_bounds__(WW) void edt_solve_row(const u64* __restrict__ zbits,
                                                    float* __restrict__ out) {
    const int rid = blockIdx.x;        // b*HH + y
    const int b = rid / HH;
    const int y = rid % HH;
    const int x = threadIdx.x;         // 0..383
    const u64* zi = zbits + b * (HH * WPR);

    const int lo = max(0, y - RSTAGE), hi = min(HH - 1, y + RSTAGE);
    const int nw = (hi - lo + 1) * WPR;           // <= 198
    __shared__ u64 sb[(2 * RSTAGE + 1) * WPR];

    // one coalesced staging burst (8B/lane), one barrier
    for (int i = x; i < nw; i += WW) sb[i] = zi[lo * WPR + i];
    __syncthreads();

    int r0 = rowdist_t(sb + (y - lo) * WPR, x);
    int best = r0 * r0;                           // == LARGE if row zero-free

    for (int dy = 1; dy < HH; ++dy) {
        int dd = dy * dy;
        if (dd >= best) break;                    // exact cutoff
        int ry = y - dy;
        if (ry >= 0) {
            int r = (ry >= lo) ? rowdist_t(sb + (ry - lo) * WPR, x)
                               : rowdist_t(zi + ry * WPR, x);   // rare tail
            best = min(best, dd + r * r);
        }
        ry = y + dy;
        if (ry < HH) {
            int r = (ry <= hi) ? rowdist_t(sb + (ry - lo) * WPR, x)
                               : rowdist_t(zi + ry * WPR, x);   // rare tail
            best = min(best, dd + r * r);
        }
    }
    out[(size_t)rid * WW + x] = sqrtf((float)best);
}

// ---------- fallback (ws too small): brute-force LDS version ----------

#define LARGE_F 589824.0f

__global__ __launch_bounds__(WW) void edt_pass1(const float* __restrict__ mask,
                                                float* __restrict__ g) {
    const int row = blockIdx.x;
    const int x = threadIdx.x;
    __shared__ float f[WW];
    f[x] = (mask[(size_t)row * WW + x] > 0.5f) ? LARGE_F : 0.0f;
    __syncthreads();
    float best = 1.0e30f;
    #pragma unroll 8
    for (int j = 0; j < WW; ++j) {
        float d = (float)(x - j);
        best = fminf(best, fmaf(d, d, f[j]));
    }
    g[(size_t)row * WW + x] = best;
}

__global__ __launch_bounds__(HH) void edt_pass2(float* __restrict__ g) {
    const int b = blockIdx.x / WW;
    const int x = blockIdx.x % WW;
    const int y = threadIdx.x;
    __shared__ float f[HH];
    f[y] = g[((size_t)b * HH + y) * WW + x];
    __syncthreads();
    float best = 1.0e30f;
    #pragma unroll 8
    for (int j = 0; j < HH; ++j) {
        float d = (float)(y - j);
        best = fminf(best, fmaf(d, d, f[j]));
    }
    g[((size_t)b * HH + y) * WW + x] = sqrtf(best);
}

extern "C" void kernel_launch(void* const* d_in, const int* in_sizes, int n_in,
                              void* d_out, int out_size, void* d_ws, size_t ws_size,
                              hipStream_t stream) {
    const float* mask = (const float*)d_in[0];
    float* out = (float*)d_out;

    if (ws_size >= (size_t)NWORDS * sizeof(u64)) {
        u64* zbits = (u64*)d_ws;
        pack_zbits<<<NPIX / 256, 256, 0, stream>>>(mask, zbits);
        edt_solve_row<<<NB * HH, WW, 0, stream>>>(zbits, out);
    } else {
        // Deterministic fallback: brute force, intermediate in d_out (in-place).
        edt_pass1<<<NB * HH, WW, 0, stream>>>(mask, out);
        edt_pass2<<<NB * WW, HH, 0, stream>>>(out);
    }
}